// Round 5
// baseline (216.912 us; speedup 1.0000x reference)
//
#include <hip/hip_runtime.h>
#include <math.h>

#define B_G   256
#define IN_D  128
#define FD    256
#define HID   256
#define OUT_D 128
#define TXT   512
#define XKS   136   // X LDS k-stride (ushorts): 272 B/row

typedef short bf16x8 __attribute__((ext_vector_type(8)));
typedef float f32x4  __attribute__((ext_vector_type(4)));

// ---------------------------------------------------------------------------
// bf16 split helpers (RNE)
// ---------------------------------------------------------------------------
__device__ __forceinline__ unsigned bf_rne(float x) {
    unsigned u = __float_as_uint(x);
    u += 0x7fffu + ((u >> 16) & 1u);
    return u >> 16;
}
__device__ __forceinline__ float bf_to_f(unsigned h) {
    return __uint_as_float(h << 16);
}
__device__ __forceinline__ void split2(float a0, float a1, unsigned& hp, unsigned& lp) {
    unsigned h0 = bf_rne(a0), h1 = bf_rne(a1);
    float r0 = a0 - bf_to_f(h0), r1 = a1 - bf_to_f(h1);
    hp = h0 | (h1 << 16);
    lp = bf_rne(r0) | (bf_rne(r1) << 16);
}

// ---------------------------------------------------------------------------
// Kernel A (grid 261): fused prep.  (unchanged)
// ---------------------------------------------------------------------------
__global__ __launch_bounds__(256) void k_prepA(
    const float* __restrict__ text_emb, const float* __restrict__ Wq,
    const float* __restrict__ bq, const float* __restrict__ Wk,
    const float* __restrict__ W0, const int* __restrict__ lens,
    float* __restrict__ qk, int* __restrict__ offsets, float* __restrict__ hsum,
    unsigned short* __restrict__ W0sH, unsigned short* __restrict__ W0sL)
{
    int blk = blockIdx.x, t = threadIdx.x;
    __shared__ float te[TXT];
    __shared__ float q[FD];
    __shared__ int   sc[B_G];

    if (blk < 256) {
        int b = blk;
        hsum[b * FD + t] = 0.f;
        for (int i = t; i < TXT; i += 256) te[i] = text_emb[(size_t)b * TXT + i];
        __syncthreads();
        float acc = bq[t];
        for (int k = 0; k < TXT; k++) acc = fmaf(te[k], Wq[k * FD + t], acc);
        q[t] = acc;
        __syncthreads();
        float a2 = 0.f;
        for (int f = 0; f < FD; f++) a2 = fmaf(Wk[t * FD + f], q[f], a2);
        qk[b * FD + t] = a2;
    } else if (blk < 260) {
        int e = (blk - 256) * 256 + t;   // 0..1023
        int kc = e >> 8, c = e & 255;
        size_t base = (size_t)(kc * 256 + c) * 32;
        for (int kk = 0; kk < 32; kk++) {
            float v = W0[(size_t)(kc * 32 + kk) * FD + c];
            unsigned h = bf_rne(v);
            float r = v - bf_to_f(h);
            W0sH[base + kk] = (unsigned short)h;
            W0sL[base + kk] = (unsigned short)bf_rne(r);
        }
    } else {
        // parallel inclusive scan of lens (256 elements, 8 steps)
        sc[t] = lens[t];
        __syncthreads();
        for (int d = 1; d < 256; d <<= 1) {
            int v = (t >= d) ? sc[t - d] : 0;
            __syncthreads();
            sc[t] += v;
            __syncthreads();
        }
        offsets[t + 1] = sc[t];
        if (t == 0) offsets[0] = 0;
    }
}

// ---------------------------------------------------------------------------
// K1: bf16x3 MFMA.  (unchanged)
// ---------------------------------------------------------------------------
__global__ __launch_bounds__(256, 4) void k_l0_mfma(
    const float* __restrict__ X,
    const unsigned short* __restrict__ W0sH, const unsigned short* __restrict__ W0sL,
    const float* __restrict__ b0, const float* __restrict__ qk,
    const int* __restrict__ offsets,
    float* __restrict__ scores, float* __restrict__ hsum)
{
    int b = blockIdx.y;
    int off = offsets[b], len = offsets[b + 1] - off;
    int n0 = blockIdx.x * 64;
    if (n0 >= len) return;
    int nvalid = min(64, len - n0);

    __shared__ __align__(16) unsigned short XsH[64 * XKS], XsL[64 * XKS]; // 2x17408 B
    __shared__ float qks[FD];
    __shared__ float bsh[FD];
    __shared__ float red[4][64];

    int tid = threadIdx.x;
    int lane = tid & 63, w = tid >> 6;
    int ln = lane & 15, quad = lane >> 4;

    qks[tid] = qk[b * FD + tid];
    bsh[tid] = b0[tid];

    // ---- stage X (full K): thread -> node tid>>2, k-range (tid&3)*32..+32 ----
    {
        int node_s = tid >> 2, ks = (tid & 3) * 32;
        const float4* Xr4 = (const float4*)(X + (size_t)(off + n0 + node_s) * IN_D + ks);
        bool v = (node_s < nvalid);
#pragma unroll
        for (int g = 0; g < 4; g++) {
            float4 a, c4;
            if (v) { a = Xr4[2 * g]; c4 = Xr4[2 * g + 1]; }
            else   { a = make_float4(0.f, 0.f, 0.f, 0.f); c4 = a; }
            uint4 hq, lq;
            split2(a.x,  a.y,  hq.x, lq.x);
            split2(a.z,  a.w,  hq.y, lq.y);
            split2(c4.x, c4.y, hq.z, lq.z);
            split2(c4.z, c4.w, hq.w, lq.w);
            *(uint4*)&XsH[node_s * XKS + ks + g * 8] = hq;
            *(uint4*)&XsL[node_s * XKS + ks + g * 8] = lq;
        }
    }
    __syncthreads();

    f32x4 acc[4][4] = {};
#pragma unroll
    for (int kc = 0; kc < 4; kc++) {
        bf16x8 AH[4], AL[4];
#pragma unroll
        for (int i = 0; i < 4; i++) {
            AH[i] = *(const bf16x8*)&XsH[(16 * i + ln) * XKS + kc * 32 + quad * 8];
            AL[i] = *(const bf16x8*)&XsL[(16 * i + ln) * XKS + kc * 32 + quad * 8];
        }
#pragma unroll
        for (int j = 0; j < 4; j++) {
            int c = 64 * w + 16 * j + ln;
            size_t base = (size_t)(kc * 256 + c) * 32 + quad * 8;
            bf16x8 BH = *(const bf16x8*)&W0sH[base];
            bf16x8 BL = *(const bf16x8*)&W0sL[base];
#pragma unroll
            for (int i = 0; i < 4; i++) {
                acc[i][j] = __builtin_amdgcn_mfma_f32_16x16x32_bf16(AH[i], BH, acc[i][j], 0, 0, 0);
                acc[i][j] = __builtin_amdgcn_mfma_f32_16x16x32_bf16(AH[i], BL, acc[i][j], 0, 0, 0);
                acc[i][j] = __builtin_amdgcn_mfma_f32_16x16x32_bf16(AL[i], BH, acc[i][j], 0, 0, 0);
            }
        }
    }

    // ---- epilogue: bias+relu+mask -> score partials & column sums ----
    float sp[4][4];
    float cs[4] = {0.f, 0.f, 0.f, 0.f};
#pragma unroll
    for (int i = 0; i < 4; i++)
#pragma unroll
        for (int r = 0; r < 4; r++) sp[i][r] = 0.f;

#pragma unroll
    for (int i = 0; i < 4; i++)
#pragma unroll
        for (int j = 0; j < 4; j++) {
            int c = 64 * w + 16 * j + ln;
            float bb = bsh[c], qv = qks[c];
#pragma unroll
            for (int r = 0; r < 4; r++) {
                int node = 16 * i + 4 * quad + r;
                float h = acc[i][j][r] + bb;
                h = (h > 0.f && node < nvalid) ? h : 0.f;
                sp[i][r] = fmaf(h, qv, sp[i][r]);
                cs[j] += h;
            }
        }
    // reduce score partials over ln (16 cols) in-wave
#pragma unroll
    for (int i = 0; i < 4; i++)
#pragma unroll
        for (int r = 0; r < 4; r++) {
            float s = sp[i][r];
            s += __shfl_xor(s, 1); s += __shfl_xor(s, 2);
            s += __shfl_xor(s, 4); s += __shfl_xor(s, 8);
            sp[i][r] = s;
        }
    if (ln == 0) {
#pragma unroll
        for (int i = 0; i < 4; i++)
#pragma unroll
            for (int r = 0; r < 4; r++)
                red[w][16 * i + 4 * quad + r] = sp[i][r];
    }
    // hsum: reduce over quads (nodes), one atomic per col
#pragma unroll
    for (int j = 0; j < 4; j++) {
        float s = cs[j];
        s += __shfl_xor(s, 16); s += __shfl_xor(s, 32);
        if (quad == 0) atomicAdd(&hsum[b * FD + 64 * w + 16 * j + ln], s);
    }
    __syncthreads();
    if (tid < 64 && tid < nvalid)
        scores[off + n0 + tid] = red[0][tid] + red[1][tid] + red[2][tid] + red[3][tid];
}

// ---------------------------------------------------------------------------
// K2a: per-graph softmax + wvec GEMV.  Writes pbuf (softmax probs) + wvec.
// ---------------------------------------------------------------------------
__global__ __launch_bounds__(1024) void k_stats(
    const float* __restrict__ scores, const float* __restrict__ hsum,
    const float* __restrict__ Wv, const float* __restrict__ bv,
    const float* __restrict__ Wo, const int* __restrict__ offsets,
    float* __restrict__ pbuf, float* __restrict__ wvecb)
{
    int b = blockIdx.x, tid = threadIdx.x;
    int t = tid & 255, g = tid >> 8;
    int off = offsets[b], len = offsets[b + 1] - off;
    __shared__ float redm[16], reds[16];
    __shared__ float hs[FD], vs[FD];
    __shared__ float part[4][FD];

    if (g == 0) hs[t] = hsum[b * FD + t];
    float s_n = (tid < len) ? scores[off + tid] : -INFINITY;

    // max
    float m = s_n;
#pragma unroll
    for (int d = 1; d < 64; d <<= 1) m = fmaxf(m, __shfl_xor(m, d));
    if ((tid & 63) == 0) redm[tid >> 6] = m;
    __syncthreads();
    m = -INFINITY;
#pragma unroll
    for (int k = 0; k < 16; k++) m = fmaxf(m, redm[k]);

    // exp + sum
    float e_n = (tid < len) ? expf(s_n - m) : 0.f;
    float s = e_n;
#pragma unroll
    for (int d = 1; d < 64; d <<= 1) s += __shfl_xor(s, d);
    if ((tid & 63) == 0) reds[tid >> 6] = s;
    __syncthreads();
    s = 0.f;
#pragma unroll
    for (int k = 0; k < 16; k++) s += reds[k];
    float dinv = 1.0f / s;
    if (tid < len) pbuf[off + tid] = e_n * dinv;

    // wvec = (hsum @ Wv + len*bv) @ Wo  (4-way split reduction)
    float acc = (g == 0) ? (float)len * bv[t] : 0.f;
    for (int f = 64 * g; f < 64 * g + 64; f++) acc = fmaf(hs[f], Wv[f * FD + t], acc);
    part[g][t] = acc;
    __syncthreads();
    if (g == 0) vs[t] = part[0][t] + part[1][t] + part[2][t] + part[3][t];
    __syncthreads();
    float a2 = 0.f;
    for (int f = 64 * g; f < 64 * g + 64; f++) a2 = fmaf(vs[f], Wo[f * HID + t], a2);
    part[g][t] = a2;
    __syncthreads();
    if (g == 0) wvecb[b * HID + t] = part[0][t] + part[1][t] + part[2][t] + part[3][t];
}

// ---------------------------------------------------------------------------
// K2b: piecewise-linear walk.  2 blocks per graph (grid 512 x 512 thr): each
// block builds the SAME op list deterministically (stable p-rank scatter, no
// atomic slotting) and walks its own 4 of 8 segments.  2 independent barrier
// domains per CU -> phase stalls decorrelate.  Unconditional 8-deep W2 ring
// prefetch (padding = zero-delta events -> harmless W2[0] loads).
// ---------------------------------------------------------------------------
__global__ __launch_bounds__(512) void k_walk(
    const float* __restrict__ pbuf, const float* __restrict__ wvecb,
    const float* __restrict__ bo, const float* __restrict__ W2,
    const float* __restrict__ b2, const int* __restrict__ offsets,
    float* __restrict__ Y)
{
    int bx = blockIdx.x;
    int b = bx >> 1, half = bx & 1;
    int tid = threadIdx.x, lane = tid & 63;
    int off = offsets[b], len = offsets[b + 1] - off;

    __shared__ float wv2[HID], boS[HID], b2s[OUT_D];
    __shared__ __align__(16) float tOrig[256];
    __shared__ float tS[256], dwS[256], dbS[256];
    __shared__ int   kS[256];
    __shared__ int   cnt[257], startS[257];
    __shared__ float A0s[OUT_D], C0s[OUT_D];
    __shared__ float segA[8][OUT_D], segC[8][OUT_D];
    __shared__ __align__(16) float ps_l[512];
    __shared__ __align__(16) int4 ops4[704];

    // ---- P0: stage vectors; node probs; zero counters ----
    if (tid < 256) { wv2[tid] = wvecb[b * HID + tid]; boS[tid] = bo[tid]; }
    if (tid < OUT_D) b2s[tid] = b2[tid];
    if (tid <= 256) cnt[tid] = 0;
    ps_l[tid] = (tid < len) ? pbuf[off + tid] : INFINITY;
    __syncthreads();

    // ---- P0b: events (active(k,p) := w*p+bo > 0 flips at t=-bo/w) ----
    bool real = false;
    if (tid < 256) {
        float wv = wv2[tid], bvv = boS[tid];
        bool isev = (wv > 0.f && bvv < 0.f) || (wv < 0.f && bvv > 0.f);
        float tk = isev ? (-bvv / wv) : INFINITY;
        real = isev && (tk < INFINITY);
        tOrig[tid] = real ? tk : INFINITY;
    }
    __syncthreads();

    // ---- P1: rank-compare event sort (tid<256) + A0/C0 partials (all) ----
    if (tid < 256) {
        float tk = tOrig[tid];
        int r = 0;
        const float4* t4 = (const float4*)tOrig;
        for (int j4 = 0; j4 < 64; ++j4) {
            float4 tj = t4[j4];
            int e0 = 4 * j4;
            r += (tj.x < tk || (tj.x == tk && (e0 + 0) < tid)) ? 1 : 0;
            r += (tj.y < tk || (tj.y == tk && (e0 + 1) < tid)) ? 1 : 0;
            r += (tj.z < tk || (tj.z == tk && (e0 + 2) < tid)) ? 1 : 0;
            r += (tj.w < tk || (tj.w == tk && (e0 + 3) < tid)) ? 1 : 0;
        }
        tS[r] = tk;
        kS[r] = tid;
        float wv = wv2[tid], bvv = boS[tid];
        dwS[r] = real ? fabsf(wv) : 0.f;
        dbS[r] = real ? -fabsf(bvv) : 0.f;
    }
    // A0/C0: active set at p->0+ is {k: bo>0 or (bo==0 && w>0)}
    {
        int q = tid >> 7, c = tid & 127;   // 4 groups x 128 cols, 64 k each
        float pa = 0.f, pc = 0.f;
        for (int k = q * 64; k < q * 64 + 64; ++k) {
            float v = W2[(size_t)k * OUT_D + c];
            float wv = wv2[k], bvv = boS[k];
            bool ini = (bvv > 0.f) || (bvv == 0.f && wv > 0.f);
            pa = fmaf(ini ? wv : 0.f, v, pa);
            pc = fmaf(ini ? bvv : 0.f, v, pc);
        }
        segA[q][c] = pa; segC[q][c] = pc;
    }
    int nE = __syncthreads_count(real);

    // ---- P2: node bucket rank + histogram; A0/C0 reduce ----
    float p_n = ps_l[tid];
    int r_n = 0;
    if (tid < len) {
        int r = 0;
#pragma unroll
        for (int st = 128; st > 0; st >>= 1)
            if (tS[r + st - 1] < p_n) r += st;
        r_n = r;
        atomicAdd(&cnt[r], 1);   // order-free histogram: deterministic result
    }
    if (tid < OUT_D) {
        A0s[tid] = segA[0][tid] + segA[1][tid] + segA[2][tid] + segA[3][tid];
        C0s[tid] = segC[0][tid] + segC[1][tid] + segC[2][tid] + segC[3][tid];
    }
    __syncthreads();

    // ---- P3: exclusive scan of cnt[0..255] by wave 0 ----
    if (tid < 64) {
        int l = tid;
        int v0 = cnt[4 * l], v1 = cnt[4 * l + 1], v2 = cnt[4 * l + 2], v3 = cnt[4 * l + 3];
        int s0 = v0, s1 = s0 + v1, s2 = s1 + v2, s3 = s2 + v3;
        int run = s3;
#pragma unroll
        for (int d = 1; d < 64; d <<= 1) {
            int t2 = __shfl_up(run, d);
            if (l >= d) run += t2;
        }
        int base = run - s3;
        startS[4 * l + 0] = base;
        startS[4 * l + 1] = base + s0;
        startS[4 * l + 2] = base + s1;
        startS[4 * l + 3] = base + s2;
        if (l == 63) startS[256] = base + s3;
    }
    __syncthreads();

    int L    = len + nE;
    int Lpad = (L + 7) & ~7;
    int Lseg = ((Lpad + 63) >> 6) << 3;   // per-segment op count, mult of 8, <=80

    // ---- P4: DETERMINISTIC op-list build.
    //  node pos = bucket_rank + stable global p-rank (identical in both blocks)
    if (tid < len) {
        int rk = 0;
        const float4* p4 = (const float4*)ps_l;
        for (int j4 = 0; j4 < 128; ++j4) {
            float4 pj = p4[j4];
            int e0 = 4 * j4;
            rk += (pj.x < p_n || (pj.x == p_n && (e0 + 0) < tid)) ? 1 : 0;
            rk += (pj.y < p_n || (pj.y == p_n && (e0 + 1) < tid)) ? 1 : 0;
            rk += (pj.z < p_n || (pj.z == p_n && (e0 + 2) < tid)) ? 1 : 0;
            rk += (pj.w < p_n || (pj.w == p_n && (e0 + 3) < tid)) ? 1 : 0;
        }
        int pos = r_n + rk;
        ops4[pos] = make_int4(__float_as_int(p_n), 0, tid, 0);
    }
    if (tid < nE) {
        int pos = startS[tid + 1] + tid;
        ops4[pos] = make_int4(__float_as_int(dwS[tid]), __float_as_int(dbS[tid]), -1, kS[tid]);
    }
    for (int i = L + tid; i < 704; i += 512)
        ops4[i] = make_int4(0, 0, -1, 0);   // zero-delta event no-op
    __syncthreads();

    // ---- P5: per-segment event deltas.  Wave w handles segment w, 2 col
    //          halves; unconditional 8-deep W2 ring prefetch. ----
    {
        int sgd = tid >> 6;                  // 8 waves -> 8 segments
        int i0 = sgd * Lseg;
        int4 cur = ops4[i0 + lane];
        int4 nxt = ops4[i0 + 64 + lane];
        const float* W2a = W2 + lane;
        const float* W2b = W2 + 64 + lane;
        float dA0 = 0.f, dC0 = 0.f, dA1 = 0.f, dC1 = 0.f;
        float rV0[8], rV1[8];
#pragma unroll
        for (int d = 0; d < 8; ++d) {
            int kU = __builtin_amdgcn_readlane(cur.w, d);
            rV0[d] = W2a[(size_t)kU * OUT_D];
            rV1[d] = W2b[(size_t)kU * OUT_D];
        }
        for (int ii = 0; ii < Lseg; ii += 8) {
            int4 rc = (ii < 64) ? cur : nxt;      int bc = ii & 63;
            int4 rp = (ii + 8 < 64) ? cur : nxt;  int bp = (ii + 8) & 63;
#pragma unroll
            for (int d = 0; d < 8; ++d) {
                int   nI = __builtin_amdgcn_readlane(rc.z, bc + d);
                float aI = __uint_as_float((unsigned)__builtin_amdgcn_readlane(rc.x, bc + d));
                float bI = __uint_as_float((unsigned)__builtin_amdgcn_readlane(rc.y, bc + d));
                int   kp = __builtin_amdgcn_readlane(rp.w, bp + d);
                float v0 = rV0[d], v1 = rV1[d];
                if (nI < 0) {
                    dA0 = fmaf(aI, v0, dA0); dC0 = fmaf(bI, v0, dC0);
                    dA1 = fmaf(aI, v1, dA1); dC1 = fmaf(bI, v1, dC1);
                }
                rV0[d] = W2a[(size_t)kp * OUT_D];
                rV1[d] = W2b[(size_t)kp * OUT_D];
            }
        }
        segA[sgd][lane] = dA0;      segC[sgd][lane] = dC0;
        segA[sgd][lane + 64] = dA1; segC[sgd][lane + 64] = dC1;
    }
    __syncthreads();

    // ---- P6: walk the 4 OWNED segments (half 0: 0-3, half 1: 4-7) ----
    {
        int sg = 4 * half + (tid >> 7);
        int c = tid & 127;
        float A = A0s[c], C = C0s[c];
        for (int s2 = 0; s2 < sg; ++s2) { A += segA[s2][c]; C += segC[s2][c]; }
        float b2v = b2s[c];
        float* Yb = Y + (size_t)off * OUT_D + c;
        int i0 = sg * Lseg;
        int4 cur = ops4[i0 + lane];
        int4 nxt = ops4[i0 + 64 + lane];
        const float* W2c = W2 + c;

        float rV[8];
#pragma unroll
        for (int d = 0; d < 8; ++d) {
            int kU = __builtin_amdgcn_readlane(cur.w, d);
            rV[d] = W2c[(size_t)kU * OUT_D];
        }
        for (int ii = 0; ii < Lseg; ii += 8) {
            int4 rc = (ii < 64) ? cur : nxt;      int bc = ii & 63;
            int4 rp = (ii + 8 < 64) ? cur : nxt;  int bp = (ii + 8) & 63;
#pragma unroll
            for (int d = 0; d < 8; ++d) {
                float aI = __uint_as_float((unsigned)__builtin_amdgcn_readlane(rc.x, bc + d));
                int   nI = __builtin_amdgcn_readlane(rc.z, bc + d);
                int   kp = __builtin_amdgcn_readlane(rp.w, bp + d);
                float vv = rV[d];
                if (nI >= 0) {
                    Yb[(size_t)nI * OUT_D] = fmaf(aI, A, C) + b2v;
                } else {
                    float bI = __uint_as_float((unsigned)__builtin_amdgcn_readlane(rc.y, bc + d));
                    A = fmaf(aI, vv, A);
                    C = fmaf(bI, vv, C);
                }
                rV[d] = W2c[(size_t)kp * OUT_D];
            }
        }
    }
}

// ---------------------------------------------------------------------------
extern "C" void kernel_launch(void* const* d_in, const int* in_sizes, int n_in,
                              void* d_out, int out_size, void* d_ws, size_t ws_size,
                              hipStream_t stream)
{
    const float* X        = (const float*)d_in[0];
    const float* text_emb = (const float*)d_in[1];
    const int*   lens     = (const int*)d_in[2];
    const float* W0       = (const float*)d_in[3];
    const float* b0       = (const float*)d_in[4];
    const float* Wq       = (const float*)d_in[5];
    const float* bq       = (const float*)d_in[6];
    const float* Wk       = (const float*)d_in[7];
    // d_in[8] = bk : softmax-invariant, unused
    const float* Wv       = (const float*)d_in[9];
    const float* bv       = (const float*)d_in[10];
    const float* Wo       = (const float*)d_in[11];
    const float* bo       = (const float*)d_in[12];
    const float* W2       = (const float*)d_in[13];
    const float* b2       = (const float*)d_in[14];
    float* Y = (float*)d_out;

    char* base = (char*)d_ws;
    size_t o = 0;
    int*   offsets = (int*)(base + o);            o += 1088;
    float* qkbuf   = (float*)(base + o);          o += 262144;
    float* hsum    = (float*)(base + o);          o += 262144;
    float* scores  = (float*)(base + o);          o += 262144;
    float* pbuf    = (float*)(base + o);          o += 262144;
    float* wvecb   = (float*)(base + o);          o += 262144;
    unsigned short* W0sH = (unsigned short*)(base + o); o += 65536;
    unsigned short* W0sL = (unsigned short*)(base + o); o += 65536;

    k_prepA<<<261, 256, 0, stream>>>(text_emb, Wq, bq, Wk, W0, lens,
                                     qkbuf, offsets, hsum, W0sH, W0sL);
    k_l0_mfma<<<dim3(6, B_G), 256, 0, stream>>>(X, W0sH, W0sL, b0, qkbuf, offsets, scores, hsum);
    k_stats<<<B_G, 1024, 0, stream>>>(scores, hsum, Wv, bv, Wo, offsets, pbuf, wvecb);
    k_walk<<<512, 512, 0, stream>>>(pbuf, wvecb, bo, W2, b2, offsets, Y);
}

// Round 6
// 201.002 us; speedup vs baseline: 1.0792x; 1.0792x over previous
//
#include <hip/hip_runtime.h>
#include <math.h>

#define B_G   256
#define IN_D  128
#define FD    256
#define HID   256
#define OUT_D 128
#define TXT   512
#define XKS   136   // X/Z LDS k-stride (ushorts): 272 B/row, 16B-aligned, <=2-way bank

typedef short bf16x8 __attribute__((ext_vector_type(8)));
typedef float f32x4  __attribute__((ext_vector_type(4)));

// ---------------------------------------------------------------------------
// bf16 split helpers (RNE)
// ---------------------------------------------------------------------------
__device__ __forceinline__ unsigned bf_rne(float x) {
    unsigned u = __float_as_uint(x);
    u += 0x7fffu + ((u >> 16) & 1u);
    return u >> 16;
}
__device__ __forceinline__ float bf_to_f(unsigned h) {
    return __uint_as_float(h << 16);
}
__device__ __forceinline__ void split2(float a0, float a1, unsigned& hp, unsigned& lp) {
    unsigned h0 = bf_rne(a0), h1 = bf_rne(a1);
    float r0 = a0 - bf_to_f(h0), r1 = a1 - bf_to_f(h1);
    hp = h0 | (h1 << 16);
    lp = bf_rne(r0) | (bf_rne(r1) << 16);
}

// ---------------------------------------------------------------------------
// Kernel A (grid 265): fused prep (R0 version: W0 + W2 splits restored).
//  blocks 0..255  : q_b = te@Wq+bq ; qk_b = Wk@q_b ; zero hsum[b]
//  blocks 256..263: split W0/W2 into fragment-layout hi/lo bf16 buffers
//                   W0s[kc=4][col=256][kk=32], W2s[kc=8][col=128][kk=32]
//  block  264     : parallel scan of lens -> offsets
// ---------------------------------------------------------------------------
__global__ __launch_bounds__(256) void k_prepA(
    const float* __restrict__ text_emb, const float* __restrict__ Wq,
    const float* __restrict__ bq, const float* __restrict__ Wk,
    const float* __restrict__ W0, const float* __restrict__ W2,
    const int* __restrict__ lens,
    float* __restrict__ qk, int* __restrict__ offsets, float* __restrict__ hsum,
    unsigned short* __restrict__ W0sH, unsigned short* __restrict__ W0sL,
    unsigned short* __restrict__ W2sH, unsigned short* __restrict__ W2sL)
{
    int blk = blockIdx.x, t = threadIdx.x;
    __shared__ float te[TXT];
    __shared__ float q[FD];
    __shared__ int   sc[B_G];

    if (blk < 256) {
        int b = blk;
        hsum[b * FD + t] = 0.f;
        for (int i = t; i < TXT; i += 256) te[i] = text_emb[(size_t)b * TXT + i];
        __syncthreads();
        float acc = bq[t];
        for (int k = 0; k < TXT; k++) acc = fmaf(te[k], Wq[k * FD + t], acc);
        q[t] = acc;
        __syncthreads();
        float a2 = 0.f;
        for (int f = 0; f < FD; f++) a2 = fmaf(Wk[t * FD + f], q[f], a2);
        qk[b * FD + t] = a2;
    } else if (blk < 264) {
        int e = (blk - 256) * 256 + t;   // 0..2047
        if (e < 1024) {
            int kc = e >> 8, c = e & 255;
            size_t base = (size_t)(kc * 256 + c) * 32;
            for (int kk = 0; kk < 32; kk++) {
                float v = W0[(size_t)(kc * 32 + kk) * FD + c];
                unsigned h = bf_rne(v);
                float r = v - bf_to_f(h);
                W0sH[base + kk] = (unsigned short)h;
                W0sL[base + kk] = (unsigned short)bf_rne(r);
            }
        } else {
            int e2 = e - 1024;
            int kc = e2 >> 7, c = e2 & 127;
            size_t base = (size_t)(kc * 128 + c) * 32;
            for (int kk = 0; kk < 32; kk++) {
                float v = W2[(size_t)(kc * 32 + kk) * OUT_D + c];
                unsigned h = bf_rne(v);
                float r = v - bf_to_f(h);
                W2sH[base + kk] = (unsigned short)h;
                W2sL[base + kk] = (unsigned short)bf_rne(r);
            }
        }
    } else {
        // parallel inclusive scan of lens (256 elements, 8 steps)
        sc[t] = lens[t];
        __syncthreads();
        for (int d = 1; d < 256; d <<= 1) {
            int v = (t >= d) ? sc[t - d] : 0;
            __syncthreads();
            sc[t] += v;
            __syncthreads();
        }
        offsets[t + 1] = sc[t];
        if (t == 0) offsets[0] = 0;
    }
}

// ---------------------------------------------------------------------------
// K1: bf16x3 MFMA, 4 blocks/CU.  (unchanged from round 3/4/5)
// ---------------------------------------------------------------------------
__global__ __launch_bounds__(256, 4) void k_l0_mfma(
    const float* __restrict__ X,
    const unsigned short* __restrict__ W0sH, const unsigned short* __restrict__ W0sL,
    const float* __restrict__ b0, const float* __restrict__ qk,
    const int* __restrict__ offsets,
    float* __restrict__ scores, float* __restrict__ hsum)
{
    int b = blockIdx.y;
    int off = offsets[b], len = offsets[b + 1] - off;
    int n0 = blockIdx.x * 64;
    if (n0 >= len) return;
    int nvalid = min(64, len - n0);

    __shared__ __align__(16) unsigned short XsH[64 * XKS], XsL[64 * XKS]; // 2x17408 B
    __shared__ float qks[FD];
    __shared__ float bsh[FD];
    __shared__ float red[4][64];

    int tid = threadIdx.x;
    int lane = tid & 63, w = tid >> 6;
    int ln = lane & 15, quad = lane >> 4;

    qks[tid] = qk[b * FD + tid];
    bsh[tid] = b0[tid];

    // ---- stage X (full K): thread -> node tid>>2, k-range (tid&3)*32..+32 ----
    {
        int node_s = tid >> 2, ks = (tid & 3) * 32;
        const float4* Xr4 = (const float4*)(X + (size_t)(off + n0 + node_s) * IN_D + ks);
        bool v = (node_s < nvalid);
#pragma unroll
        for (int g = 0; g < 4; g++) {
            float4 a, c4;
            if (v) { a = Xr4[2 * g]; c4 = Xr4[2 * g + 1]; }
            else   { a = make_float4(0.f, 0.f, 0.f, 0.f); c4 = a; }
            uint4 hq, lq;
            split2(a.x,  a.y,  hq.x, lq.x);
            split2(a.z,  a.w,  hq.y, lq.y);
            split2(c4.x, c4.y, hq.z, lq.z);
            split2(c4.z, c4.w, hq.w, lq.w);
            *(uint4*)&XsH[node_s * XKS + ks + g * 8] = hq;
            *(uint4*)&XsL[node_s * XKS + ks + g * 8] = lq;
        }
    }
    __syncthreads();

    f32x4 acc[4][4] = {};
#pragma unroll
    for (int kc = 0; kc < 4; kc++) {
        bf16x8 AH[4], AL[4];
#pragma unroll
        for (int i = 0; i < 4; i++) {
            AH[i] = *(const bf16x8*)&XsH[(16 * i + ln) * XKS + kc * 32 + quad * 8];
            AL[i] = *(const bf16x8*)&XsL[(16 * i + ln) * XKS + kc * 32 + quad * 8];
        }
#pragma unroll
        for (int j = 0; j < 4; j++) {
            int c = 64 * w + 16 * j + ln;
            size_t base = (size_t)(kc * 256 + c) * 32 + quad * 8;
            bf16x8 BH = *(const bf16x8*)&W0sH[base];
            bf16x8 BL = *(const bf16x8*)&W0sL[base];
#pragma unroll
            for (int i = 0; i < 4; i++) {
                acc[i][j] = __builtin_amdgcn_mfma_f32_16x16x32_bf16(AH[i], BH, acc[i][j], 0, 0, 0);
                acc[i][j] = __builtin_amdgcn_mfma_f32_16x16x32_bf16(AH[i], BL, acc[i][j], 0, 0, 0);
                acc[i][j] = __builtin_amdgcn_mfma_f32_16x16x32_bf16(AL[i], BH, acc[i][j], 0, 0, 0);
            }
        }
    }

    // ---- epilogue: bias+relu+mask -> score partials & column sums ----
    float sp[4][4];
    float cs[4] = {0.f, 0.f, 0.f, 0.f};
#pragma unroll
    for (int i = 0; i < 4; i++)
#pragma unroll
        for (int r = 0; r < 4; r++) sp[i][r] = 0.f;

#pragma unroll
    for (int i = 0; i < 4; i++)
#pragma unroll
        for (int j = 0; j < 4; j++) {
            int c = 64 * w + 16 * j + ln;
            float bb = bsh[c], qv = qks[c];
#pragma unroll
            for (int r = 0; r < 4; r++) {
                int node = 16 * i + 4 * quad + r;
                float h = acc[i][j][r] + bb;
                h = (h > 0.f && node < nvalid) ? h : 0.f;
                sp[i][r] = fmaf(h, qv, sp[i][r]);
                cs[j] += h;
            }
        }
    // reduce score partials over ln (16 cols) in-wave
#pragma unroll
    for (int i = 0; i < 4; i++)
#pragma unroll
        for (int r = 0; r < 4; r++) {
            float s = sp[i][r];
            s += __shfl_xor(s, 1); s += __shfl_xor(s, 2);
            s += __shfl_xor(s, 4); s += __shfl_xor(s, 8);
            sp[i][r] = s;
        }
    if (ln == 0) {
#pragma unroll
        for (int i = 0; i < 4; i++)
#pragma unroll
            for (int r = 0; r < 4; r++)
                red[w][16 * i + 4 * quad + r] = sp[i][r];
    }
    // hsum: reduce over quads (nodes), one atomic per col
#pragma unroll
    for (int j = 0; j < 4; j++) {
        float s = cs[j];
        s += __shfl_xor(s, 16); s += __shfl_xor(s, 32);
        if (quad == 0) atomicAdd(&hsum[b * FD + 64 * w + 16 * j + ln], s);
    }
    __syncthreads();
    if (tid < 64 && tid < nvalid)
        scores[off + n0 + tid] = red[0][tid] + red[1][tid] + red[2][tid] + red[3][tid];
}

// ---------------------------------------------------------------------------
// K2: per-graph softmax stats + w_b = (hsum_b @ Wv + len*bv) @ Wo  (R0 version)
// ---------------------------------------------------------------------------
__global__ __launch_bounds__(1024) void k_graph(
    const float* __restrict__ scores, const float* __restrict__ hsum,
    const float* __restrict__ Wv, const float* __restrict__ bv,
    const float* __restrict__ Wo, const int* __restrict__ offsets,
    float* __restrict__ wvec, float* __restrict__ smax, float* __restrict__ dinv)
{
    int b = blockIdx.x, tid = threadIdx.x;
    int t = tid & 255, g = tid >> 8;
    int off = offsets[b], len = offsets[b + 1] - off;
    __shared__ float redm[16], reds[16];
    __shared__ float hs[FD], vs[FD];
    __shared__ float part[4][FD];

    float m = -INFINITY;
    for (int i = tid; i < len; i += 1024) m = fmaxf(m, scores[off + i]);
    for (int d = 1; d < 64; d <<= 1) m = fmaxf(m, __shfl_xor(m, d));
    if ((tid & 63) == 0) redm[tid >> 6] = m;
    __syncthreads();
    m = -INFINITY;
#pragma unroll
    for (int k = 0; k < 16; k++) m = fmaxf(m, redm[k]);

    float s = 0.f;
    for (int i = tid; i < len; i += 1024) s += expf(scores[off + i] - m);
    for (int d = 1; d < 64; d <<= 1) s += __shfl_xor(s, d);
    if ((tid & 63) == 0) reds[tid >> 6] = s;
    if (g == 0) hs[t] = hsum[b * FD + t];
    __syncthreads();
    s = 0.f;
#pragma unroll
    for (int k = 0; k < 16; k++) s += reds[k];

    float acc = (g == 0) ? (float)len * bv[t] : 0.f;
    for (int f = 64 * g; f < 64 * g + 64; f++) acc = fmaf(hs[f], Wv[f * FD + t], acc);
    part[g][t] = acc;
    __syncthreads();
    if (g == 0) vs[t] = part[0][t] + part[1][t] + part[2][t] + part[3][t];
    __syncthreads();
    float a2 = 0.f;
    for (int f = 64 * g; f < 64 * g + 64; f++) a2 = fmaf(vs[f], Wo[f * HID + t], a2);
    part[g][t] = a2;
    __syncthreads();
    if (g == 0) wvec[b * HID + t] = part[0][t] + part[1][t] + part[2][t] + part[3][t];
    if (tid == 0) { smax[b] = m; dinv[b] = 1.0f / s; }
}

// ---------------------------------------------------------------------------
// K3: bf16x3 MFMA fin, v2: K-TILED Z (2 halves of 128) -> LDS 70.6 -> 37.6 KB
// -> 4 blocks/CU (__launch_bounds__(256,4)).  Z is GENERATED from registers
// (relu(p*w+bo)), so regenerating per half costs only 2 extra barriers.
// ---------------------------------------------------------------------------
__global__ __launch_bounds__(256, 4) void k_fin_mfma(
    const float* __restrict__ scores, const float* __restrict__ wvec,
    const float* __restrict__ bo,
    const unsigned short* __restrict__ W2sH, const unsigned short* __restrict__ W2sL,
    const float* __restrict__ b2, const float* __restrict__ smax,
    const float* __restrict__ dinv, const int* __restrict__ offsets,
    float* __restrict__ Y)
{
    int b = blockIdx.y;
    int off = offsets[b], len = offsets[b + 1] - off;
    int n0 = blockIdx.x * 64;
    if (n0 >= len) return;
    int nvalid = min(64, len - n0);

    int tid = threadIdx.x;
    int lane = tid & 63, w = tid >> 6;
    int ln = lane & 15, quad = lane >> 4;

    __shared__ __align__(16) unsigned short ZsH[64 * XKS], ZsL[64 * XKS]; // 2x17408 B
    __shared__ float ps[64];
    __shared__ float wsh[HID];
    __shared__ float bosh[HID];
    __shared__ float b2sh[OUT_D];

    wsh[tid] = wvec[b * HID + tid];
    bosh[tid] = bo[tid];
    if (tid < OUT_D) b2sh[tid] = b2[tid];
    if (tid < 64) {
        float p = 0.f;
        if (tid < nvalid) p = expf(scores[off + n0 + tid] - smax[b]) * dinv[b];
        ps[tid] = p;
    }
    __syncthreads();

    f32x4 acc[4][2] = {};
    int node_s = tid >> 2, ks = (tid & 3) * 32;   // staging role (local k in half)

#pragma unroll
    for (int h = 0; h < 2; h++) {
        if (h) __syncthreads();   // protect LDS overwrite vs previous MFMA reads
        // ---- generate Z half [64 nodes][128 k]: k_global = h*128 + local ----
        {
            float pn = ps[node_s];
            int kg0 = h * 128 + ks;
#pragma unroll
            for (int g = 0; g < 4; g++) {
                uint4 hq, lq;
                int kb = kg0 + g * 8;
                float z0, z1;
                z0 = fmaxf(fmaf(pn, wsh[kb + 0], bosh[kb + 0]), 0.f);
                z1 = fmaxf(fmaf(pn, wsh[kb + 1], bosh[kb + 1]), 0.f);
                split2(z0, z1, hq.x, lq.x);
                z0 = fmaxf(fmaf(pn, wsh[kb + 2], bosh[kb + 2]), 0.f);
                z1 = fmaxf(fmaf(pn, wsh[kb + 3], bosh[kb + 3]), 0.f);
                split2(z0, z1, hq.y, lq.y);
                z0 = fmaxf(fmaf(pn, wsh[kb + 4], bosh[kb + 4]), 0.f);
                z1 = fmaxf(fmaf(pn, wsh[kb + 5], bosh[kb + 5]), 0.f);
                split2(z0, z1, hq.z, lq.z);
                z0 = fmaxf(fmaf(pn, wsh[kb + 6], bosh[kb + 6]), 0.f);
                z1 = fmaxf(fmaf(pn, wsh[kb + 7], bosh[kb + 7]), 0.f);
                split2(z0, z1, hq.w, lq.w);
                *(uint4*)&ZsH[node_s * XKS + ks + g * 8] = hq;
                *(uint4*)&ZsL[node_s * XKS + ks + g * 8] = lq;
            }
        }
        __syncthreads();

        // ---- MFMA over this half: kc_local 0..3, kc_global = h*4+kc ----
#pragma unroll
        for (int kc = 0; kc < 4; kc++) {
            bf16x8 AH[4], AL[4];
#pragma unroll
            for (int i = 0; i < 4; i++) {
                AH[i] = *(const bf16x8*)&ZsH[(16 * i + ln) * XKS + kc * 32 + quad * 8];
                AL[i] = *(const bf16x8*)&ZsL[(16 * i + ln) * XKS + kc * 32 + quad * 8];
            }
#pragma unroll
            for (int j = 0; j < 2; j++) {
                int c = 32 * w + 16 * j + ln;
                size_t base = (size_t)((h * 4 + kc) * 128 + c) * 32 + quad * 8;
                bf16x8 BH = *(const bf16x8*)&W2sH[base];
                bf16x8 BL = *(const bf16x8*)&W2sL[base];
#pragma unroll
                for (int i = 0; i < 4; i++) {
                    acc[i][j] = __builtin_amdgcn_mfma_f32_16x16x32_bf16(AH[i], BH, acc[i][j], 0, 0, 0);
                    acc[i][j] = __builtin_amdgcn_mfma_f32_16x16x32_bf16(AH[i], BL, acc[i][j], 0, 0, 0);
                    acc[i][j] = __builtin_amdgcn_mfma_f32_16x16x32_bf16(AL[i], BH, acc[i][j], 0, 0, 0);
                }
            }
        }
    }

    // ---- epilogue: + b2, masked store ----
#pragma unroll
    for (int i = 0; i < 4; i++)
#pragma unroll
        for (int j = 0; j < 2; j++) {
            int c = 32 * w + 16 * j + ln;
            float bb = b2sh[c];
#pragma unroll
            for (int r = 0; r < 4; r++) {
                int node = 16 * i + 4 * quad + r;
                if (node < nvalid)
                    Y[(size_t)(off + n0 + node) * OUT_D + c] = acc[i][j][r] + bb;
            }
        }
}

// ---------------------------------------------------------------------------
extern "C" void kernel_launch(void* const* d_in, const int* in_sizes, int n_in,
                              void* d_out, int out_size, void* d_ws, size_t ws_size,
                              hipStream_t stream)
{
    const float* X        = (const float*)d_in[0];
    const float* text_emb = (const float*)d_in[1];
    const int*   lens     = (const int*)d_in[2];
    const float* W0       = (const float*)d_in[3];
    const float* b0       = (const float*)d_in[4];
    const float* Wq       = (const float*)d_in[5];
    const float* bq       = (const float*)d_in[6];
    const float* Wk       = (const float*)d_in[7];
    // d_in[8] = bk : softmax-invariant, unused
    const float* Wv       = (const float*)d_in[9];
    const float* bv       = (const float*)d_in[10];
    const float* Wo       = (const float*)d_in[11];
    const float* bo       = (const float*)d_in[12];
    const float* W2       = (const float*)d_in[13];
    const float* b2       = (const float*)d_in[14];
    float* Y = (float*)d_out;

    char* base = (char*)d_ws;
    size_t o = 0;
    int*   offsets = (int*)(base + o);            o += 1088;
    float* qkbuf   = (float*)(base + o);          o += 262144;
    float* wvecb   = (float*)(base + o);          o += 262144;
    float* smaxb   = (float*)(base + o);          o += 1024;
    float* dinvb   = (float*)(base + o);          o += 1024;
    float* hsum    = (float*)(base + o);          o += 262144;
    float* scores  = (float*)(base + o);          o += 262144;
    unsigned short* W0sH = (unsigned short*)(base + o); o += 65536;
    unsigned short* W0sL = (unsigned short*)(base + o); o += 65536;
    unsigned short* W2sH = (unsigned short*)(base + o); o += 65536;
    unsigned short* W2sL = (unsigned short*)(base + o); o += 65536;

    k_prepA<<<265, 256, 0, stream>>>(text_emb, Wq, bq, Wk, W0, W2, lens,
                                     qkbuf, offsets, hsum, W0sH, W0sL, W2sH, W2sL);
    k_l0_mfma<<<dim3(6, B_G), 256, 0, stream>>>(X, W0sH, W0sL, b0, qkbuf, offsets, scores, hsum);
    k_graph<<<B_G, 1024, 0, stream>>>(scores, hsum, Wv, bv, Wo, offsets, wvecb, smaxb, dinvb);
    k_fin_mfma<<<dim3(6, B_G), 256, 0, stream>>>(scores, wvecb, bo, W2sH, W2sL, b2, smaxb, dinvb, offsets, Y);
}